// Round 1
// baseline (60.420 us; speedup 1.0000x reference)
//
#include <hip/hip_runtime.h>
#include <math.h>

#define BIG_NEG (-1.0e9f)

constexpr int B = 16, T = 2048, D = 64, C = 32, NF = 16;

// ws layout (floats):
//   [0..63]               inv_var
//   [64]                  log_norm
//   [128 .. 128+K*C)      length_lp  (K*C = 640)
//   [1024 .. 1024+B*T*C)  emission   (1,048,576)
//   [.. + B*(T+1)*C)      cs         (1,049,088)
// total ~ 8.4 MB

// ---------------------------------------------------------------------------
// prep: inv_var, log_norm, length_lp table, trans_lp (C x C), init_lp (C)
// one block of 1024 threads
// ---------------------------------------------------------------------------
__global__ __launch_bounds__(1024) void prep_kernel(
    const float* __restrict__ P,       // (D,NF)
    const float* __restrict__ TL,      // (C,D)
    const float* __restrict__ TR,      // (C,D)
    const float* __restrict__ STD,     // (D,)
    const float* __restrict__ PLR,     // (C,)
    const float* __restrict__ LOGITS,  // (C,)
    float* __restrict__ ws,
    float* __restrict__ out_trans,     // (C,C)
    float* __restrict__ out_init,      // (C,)
    int K)
{
    __shared__ float left[C][NF];
    __shared__ float right[C][NF];
    __shared__ float M[C][C + 1];
    __shared__ float lse[C];
    __shared__ float ilse;

    const int tid = threadIdx.x;

    // inv_var
    if (tid < D) {
        float s = STD[tid];
        ws[tid] = 1.0f / (s * s);
    }
    // log_norm = -sum(log(std)) - 0.5*D*log(2*pi)
    if (tid == 0) {
        float acc = 0.0f;
        for (int d = 0; d < D; ++d) acc += logf(STD[d]);
        ws[64] = -acc - 58.81206612510332f;  // 0.5*64*log(2*pi)
    }
    // left/right projections (C x NF), 512 threads
    if (tid < C * NF) {
        int c = tid >> 4, f = tid & (NF - 1);
        float aL = 0.0f, aR = 0.0f;
        for (int d = 0; d < D; ++d) {
            float p = P[d * NF + f];
            aL = fmaf(TL[c * D + d], p, aL);
            aR = fmaf(TR[c * D + d], p, aR);
        }
        left[c][f] = aL;
        right[c][f] = aR;
    }
    __syncthreads();

    // M[i][j] = sum_f right[i][f] * left[j][f]   (1024 threads)
    {
        int i = tid >> 5, j = tid & 31;
        float acc = 0.0f;
        for (int f = 0; f < NF; ++f) acc = fmaf(right[i][f], left[j][f], acc);
        M[i][j] = acc;
    }
    __syncthreads();

    // column logsumexp over i (axis=0), one thread per column j
    if (tid < C) {
        int j = tid;
        float mx = -INFINITY;
        for (int i = 0; i < C; ++i) mx = fmaxf(mx, M[i][j]);
        float s = 0.0f;
        for (int i = 0; i < C; ++i) s += expf(M[i][j] - mx);
        lse[j] = logf(s) + mx;
    }
    // init logsumexp (serial by one thread; C=32 trivial)
    if (tid == 32) {
        float mx = -INFINITY;
        for (int i = 0; i < C; ++i) mx = fmaxf(mx, LOGITS[i]);
        float s = 0.0f;
        for (int i = 0; i < C; ++i) s += expf(LOGITS[i] - mx);
        ilse = logf(s) + mx;
    }
    __syncthreads();

    // write trans_lp
    {
        int i = tid >> 5, j = tid & 31;
        out_trans[i * C + j] = M[i][j] - lse[j];
    }
    // write init_lp
    if (tid < C) out_init[tid] = LOGITS[tid] - ilse;

    // length_lp[k][c] = (k+1)*plr[c] - exp(plr[c]) - lgamma(k+2)
    if (tid < K * C) {
        int k = tid >> 5, c = tid & 31;
        float plr = PLR[c];
        float kk = (float)(k + 1);
        ws[128 + tid] = kk * plr - expf(plr) - lgammaf(kk + 1.0f);
    }
}

// ---------------------------------------------------------------------------
// emission: (B,T,C); block handles 8 (b,t) pairs x 32 classes
// ---------------------------------------------------------------------------
__global__ __launch_bounds__(256) void emission_kernel(
    const float* __restrict__ feat,    // (B,T,D)
    const float* __restrict__ means,   // (C,D)
    const float* __restrict__ ws,
    float* __restrict__ em)            // (B,T,C)
{
    __shared__ float f_lds[8 * 64];
    __shared__ float m_lds[C * 65];    // padded stride 65 -> conflict-free
    __shared__ float iv[D];

    const int tid = threadIdx.x;
    const int blk = blockIdx.x;        // B*T/8 blocks

    const float* fbase = feat + (size_t)blk * 512;
    f_lds[tid] = fbase[tid];
    f_lds[tid + 256] = fbase[tid + 256];
    for (int i = tid; i < C * D; i += 256) {
        int c = i >> 6, d = i & 63;
        m_lds[c * 65 + d] = means[i];
    }
    if (tid < D) iv[tid] = ws[tid];
    float log_norm = ws[64];
    __syncthreads();

    const int p = tid >> 5, c = tid & 31;
    const float* f = &f_lds[p * 64];
    const float* m = &m_lds[c * 65];
    float acc = 0.0f;
#pragma unroll
    for (int d = 0; d < D; ++d) {
        float df = f[d] - m[d];
        acc = fmaf(df * df, iv[d], acc);
    }
    em[(size_t)blk * 256 + tid] = -0.5f * acc + log_norm;
}

// ---------------------------------------------------------------------------
// scan: cumsum over T per (b,c); block = (b,c), 256 threads x 8 t each
// cs has T+1 entries per (b,c), cs[0] = 0
// ---------------------------------------------------------------------------
__global__ __launch_bounds__(256) void scan_kernel(
    const float* __restrict__ em,      // (B,T,C)
    float* __restrict__ cs)            // (B,T+1,C)
{
    __shared__ float sums[256];
    const int tid = threadIdx.x;
    const int b = blockIdx.x >> 5, c = blockIdx.x & 31;

    const float* ebase = em + ((size_t)b * T) * C + c;
    float loc[8];
    float run = 0.0f;
    const int t0 = tid * 8;
#pragma unroll
    for (int j = 0; j < 8; ++j) {
        run += ebase[(size_t)(t0 + j) * C];
        loc[j] = run;
    }
    sums[tid] = run;
    __syncthreads();
    for (int off = 1; off < 256; off <<= 1) {
        float v = (tid >= off) ? sums[tid - off] : 0.0f;
        __syncthreads();
        sums[tid] += v;
        __syncthreads();
    }
    const float excl = sums[tid] - run;

    float* cbase = cs + ((size_t)b * (T + 1)) * C + c;
    if (tid == 0) cbase[0] = 0.0f;
#pragma unroll
    for (int j = 0; j < 8; ++j)
        cbase[(size_t)(t0 + j + 1) * C] = excl + loc[j];
}

// ---------------------------------------------------------------------------
// span: out[b,k,t,c] = (t>=k ? cs[b,t+1,c]-cs[b,t-k,c] : BIG_NEG) + llp[k,c]
// float4 per thread over c, fully coalesced stores
// ---------------------------------------------------------------------------
__global__ __launch_bounds__(256) void span_kernel(
    const float* __restrict__ cs,
    const float* __restrict__ llp,
    float* __restrict__ out,
    int K, int total4)
{
    const int stride = gridDim.x * blockDim.x;
    for (int u = blockIdx.x * blockDim.x + threadIdx.x; u < total4; u += stride) {
        const int c = (u & 7) << 2;
        const int rest = u >> 3;
        const int t = rest & (T - 1);
        const int bk = rest >> 11;
        const int k = bk % K;
        const int b = bk / K;

        const float4 lv = *(const float4*)&llp[k * C + c];
        const int start = t - k;
        float4 r;
        if (start >= 0) {
            const float4 e = *(const float4*)&cs[((size_t)(b * (T + 1) + t + 1)) * C + c];
            const float4 s = *(const float4*)&cs[((size_t)(b * (T + 1) + start)) * C + c];
            r = make_float4(e.x - s.x + lv.x, e.y - s.y + lv.y,
                            e.z - s.z + lv.z, e.w - s.w + lv.w);
        } else {
            r = make_float4(BIG_NEG + lv.x, BIG_NEG + lv.y,
                            BIG_NEG + lv.z, BIG_NEG + lv.w);
        }
        *(float4*)&out[(size_t)u * 4] = r;
    }
}

// ---------------------------------------------------------------------------
extern "C" void kernel_launch(void* const* d_in, const int* in_sizes, int n_in,
                              void* d_out, int out_size, void* d_ws, size_t ws_size,
                              hipStream_t stream) {
    const float* feat   = (const float*)d_in[0];
    const float* P      = (const float*)d_in[1];
    const float* TL     = (const float*)d_in[2];
    const float* TR     = (const float*)d_in[3];
    const float* MEANS  = (const float*)d_in[4];
    const float* STDV   = (const float*)d_in[5];
    const float* PLR    = (const float*)d_in[6];
    const float* LOGITS = (const float*)d_in[7];

    // K is a device scalar; derive it host-side from out_size instead.
    const int K = (out_size - (C * C + C)) / (B * T * C);

    float* ws  = (float*)d_ws;
    float* llp = ws + 128;
    float* em  = ws + 1024;
    float* cs  = em + (size_t)B * T * C;

    float* out       = (float*)d_out;
    float* out_trans = out + (size_t)B * K * T * C;
    float* out_init  = out_trans + C * C;

    prep_kernel<<<1, 1024, 0, stream>>>(P, TL, TR, STDV, PLR, LOGITS,
                                        ws, out_trans, out_init, K);
    emission_kernel<<<B * T / 8, 256, 0, stream>>>(feat, MEANS, ws, em);
    scan_kernel<<<B * C, 256, 0, stream>>>(em, cs);

    const int total4 = B * K * T * C / 4;
    span_kernel<<<4096, 256, 0, stream>>>(cs, llp, out, K, total4);
}